// Round 13
// baseline (54.110 us; speedup 1.0000x reference)
//
#include <hip/hip_runtime.h>
#include <hip/hip_fp16.h>

#define B_ 2048
#define F_ 4096
#define C_ 8192
#define T_ 8
#define K_ 1024
#define S_ 8
#define RROWS 8
#define TPB 1024

// ---------------------------------------------------------------------------
// Balanced prepass. klit[s][k] = 8 packed u16 LDS-slot indices ((f<<1)|sgn)
// of the literals of conjunction class_conj[k][s], REORDERED so that across
// each 64-lane wave (classes k in [w*64,w*64+64)) the bank-groups (slot&7)
// at each literal position j are balanced (greedy, 8 sub-rounds of 8 lanes).
// Product is commutative, so any per-conjunction order is exact.
// Grid: 8*16=128 blocks x 64 threads; block = (wgrp, s).
// ---------------------------------------------------------------------------
__global__ __launch_bounds__(64) void build_klit_balanced(
    const int* __restrict__ feat,
    const int* __restrict__ sign,
    const int* __restrict__ class_conj,
    uint4* __restrict__ klit)
{
    const int s    = blockIdx.x & 7;
    const int wgrp = blockIdx.x >> 3;          // 0..15
    const int tid  = threadIdx.x;              // 0..63
    const int kk   = wgrp * 64 + tid;

    const int c = class_conj[kk * S_ + s];
    const int4* fq = (const int4*)(feat + c * T_);
    const int4* sq = (const int4*)(sign + c * T_);
    int4 f0 = fq[0], f1 = fq[1];
    int4 s0 = sq[0], s1 = sq[1];
    unsigned slots[T_];
    slots[0] = (unsigned)((f0.x << 1) | (s0.x > 0 ? 1 : 0));
    slots[1] = (unsigned)((f0.y << 1) | (s0.y > 0 ? 1 : 0));
    slots[2] = (unsigned)((f0.z << 1) | (s0.z > 0 ? 1 : 0));
    slots[3] = (unsigned)((f0.w << 1) | (s0.w > 0 ? 1 : 0));
    slots[4] = (unsigned)((f1.x << 1) | (s1.x > 0 ? 1 : 0));
    slots[5] = (unsigned)((f1.y << 1) | (s1.y > 0 ? 1 : 0));
    slots[6] = (unsigned)((f1.z << 1) | (s1.z > 0 ? 1 : 0));
    slots[7] = (unsigned)((f1.w << 1) | (s1.w > 0 ? 1 : 0));

    __shared__ int cnt[8];
    unsigned used = 0;
    unsigned chosen[T_];

    for (int j = 0; j < T_; ++j) {
        if (tid < 8) cnt[tid] = 0;
        __syncthreads();
        for (int r = 0; r < 8; ++r) {
            if ((tid & 7) == r) {
                int best = -1, bc = 1 << 30;
                const int rot = tid >> 3;              // vary tie-breaking
                #pragma unroll
                for (int ii = 0; ii < T_; ++ii) {
                    int i = (ii + rot) & 7;
                    if (!((used >> i) & 1u)) {
                        int cg = cnt[slots[i] & 7];
                        if (cg < bc) { bc = cg; best = i; }
                    }
                }
                used |= 1u << best;
                chosen[j] = slots[best];
                atomicAdd(&cnt[(int)(slots[best] & 7)], 1);
            }
            __syncthreads();
        }
    }

    uint4 p;
    p.x = (chosen[0] & 0xFFFFu) | (chosen[1] << 16);
    p.y = (chosen[2] & 0xFFFFu) | (chosen[3] << 16);
    p.z = (chosen[4] & 0xFFFFu) | (chosen[5] << 16);
    p.w = (chosen[6] & 0xFFFFu) | (chosen[7] << 16);
    klit[s * K_ + kk] = p;
}

// packed f16 max: ROCm 7.2 lacks __hmax2; gfx950 has v_pk_max_f16
__device__ __forceinline__ __half2 h2max(__half2 a, __half2 b) {
    unsigned int ua = *(unsigned int*)&a, ub = *(unsigned int*)&b, ur;
    asm("v_pk_max_f16 %0, %1, %2" : "=v"(ur) : "v"(ua), "v"(ub));
    return *(__half2*)&ur;
}

__device__ __forceinline__ __half2 u2h2(unsigned int u) { return *(__half2*)&u; }

// one literal for 8 rows: ONE ds_read_b128 at slot index (direct LDS indexing)
#define LIT_INIT(SLOT)                                              \
    { uint4 g = xs4[SLOT];                                          \
      pa = u2h2(g.x); pb = u2h2(g.y); pc = u2h2(g.z); pd = u2h2(g.w); }
#define LIT_MUL(SLOT)                                               \
    { uint4 g = xs4[SLOT];                                          \
      pa = __hmul2(pa, u2h2(g.x)); pb = __hmul2(pb, u2h2(g.y));     \
      pc = __hmul2(pc, u2h2(g.z)); pd = __hmul2(pd, u2h2(g.w)); }

// one s-step: product of 8 literals (packed in uint4 P), max into m*
#define STEP_FIRST(P)                                               \
    { __half2 pa, pb, pc, pd;                                       \
      LIT_INIT((P).x & 0xFFFFu); LIT_MUL((P).x >> 16);              \
      LIT_MUL ((P).y & 0xFFFFu); LIT_MUL((P).y >> 16);              \
      LIT_MUL ((P).z & 0xFFFFu); LIT_MUL((P).z >> 16);              \
      LIT_MUL ((P).w & 0xFFFFu); LIT_MUL((P).w >> 16);              \
      ma = pa; mb = pb; mc = pc; md = pd; }
#define STEP_NEXT(P)                                                \
    { __half2 pa, pb, pc, pd;                                       \
      LIT_INIT((P).x & 0xFFFFu); LIT_MUL((P).x >> 16);              \
      LIT_MUL ((P).y & 0xFFFFu); LIT_MUL((P).y >> 16);              \
      LIT_MUL ((P).z & 0xFFFFu); LIT_MUL((P).z >> 16);              \
      LIT_MUL ((P).w & 0xFFFFu); LIT_MUL((P).w >> 16);              \
      ma = h2max(ma, pa); mb = h2max(mb, pb);                       \
      mc = h2max(mc, pc); md = h2max(md, pd); }

// ---------------------------------------------------------------------------
// Fused kernel: one 1024-thread block per 8 batch rows; grid=256 = 1 block/CU.
// LDS: one uint4 per (f,s) slot = 8 rows f16 = 128 KB.
// klit loads for all 8 steps hoisted before staging (overlap HBM latency).
// ---------------------------------------------------------------------------
__global__ __launch_bounds__(TPB, 4) void dnf_kernel(
    const float* __restrict__ x,
    const uint4* __restrict__ klit,
    float* __restrict__ out)
{
    __shared__ __align__(16) uint4 xs4[F_ * 2];   // 128 KB: slot = (f<<1)|s

    const int b0  = blockIdx.x * RROWS;
    const int tid = threadIdx.x;
    const int kk  = tid;                          // one class per thread

    // hoisted coalesced index loads (overlap the staging HBM phase)
    uint4 kl0 = klit[0 * K_ + kk];
    uint4 kl1 = klit[1 * K_ + kk];
    uint4 kl2 = klit[2 * K_ + kk];
    uint4 kl3 = klit[3 * K_ + kk];
    uint4 kl4 = klit[4 * K_ + kk];
    uint4 kl5 = klit[5 * K_ + kk];
    uint4 kl6 = klit[6 * K_ + kk];
    uint4 kl7 = klit[7 * K_ + kk];

    // ---- stage 8 rows of x as dual f16 table ----
    for (int f = tid; f < F_; f += TPB) {
        float v0 = x[(size_t)(b0 + 0) * F_ + f];
        float v1 = x[(size_t)(b0 + 1) * F_ + f];
        float v2 = x[(size_t)(b0 + 2) * F_ + f];
        float v3 = x[(size_t)(b0 + 3) * F_ + f];
        float v4 = x[(size_t)(b0 + 4) * F_ + f];
        float v5 = x[(size_t)(b0 + 5) * F_ + f];
        float v6 = x[(size_t)(b0 + 6) * F_ + f];
        float v7 = x[(size_t)(b0 + 7) * F_ + f];
        __half2 n01 = __floats2half2_rn(1.0f - v0, 1.0f - v1);
        __half2 n23 = __floats2half2_rn(1.0f - v2, 1.0f - v3);
        __half2 n45 = __floats2half2_rn(1.0f - v4, 1.0f - v5);
        __half2 n67 = __floats2half2_rn(1.0f - v6, 1.0f - v7);
        __half2 p01 = __floats2half2_rn(v0, v1);
        __half2 p23 = __floats2half2_rn(v2, v3);
        __half2 p45 = __floats2half2_rn(v4, v5);
        __half2 p67 = __floats2half2_rn(v6, v7);
        uint4 neg, pos;
        neg.x = *(unsigned*)&n01; neg.y = *(unsigned*)&n23;
        neg.z = *(unsigned*)&n45; neg.w = *(unsigned*)&n67;
        pos.x = *(unsigned*)&p01; pos.y = *(unsigned*)&p23;
        pos.z = *(unsigned*)&p45; pos.w = *(unsigned*)&p67;
        xs4[(f << 1) | 0] = neg;
        xs4[(f << 1) | 1] = pos;
    }
    __syncthreads();

    __half2 ma, mb, mc, md;
    STEP_FIRST(kl0);
    STEP_NEXT(kl1);
    STEP_NEXT(kl2);
    STEP_NEXT(kl3);
    STEP_NEXT(kl4);
    STEP_NEXT(kl5);
    STEP_NEXT(kl6);
    STEP_NEXT(kl7);

    float2 f;
    f = __half22float2(ma); out[(size_t)(b0+0)*K_+kk] = f.x; out[(size_t)(b0+1)*K_+kk] = f.y;
    f = __half22float2(mb); out[(size_t)(b0+2)*K_+kk] = f.x; out[(size_t)(b0+3)*K_+kk] = f.y;
    f = __half22float2(mc); out[(size_t)(b0+4)*K_+kk] = f.x; out[(size_t)(b0+5)*K_+kk] = f.y;
    f = __half22float2(md); out[(size_t)(b0+6)*K_+kk] = f.x; out[(size_t)(b0+7)*K_+kk] = f.y;
}

// ---------------------------------------------------------------------------
// Fallback (no workspace): inline feat/sign decode, same LDS table.
// ---------------------------------------------------------------------------
__global__ __launch_bounds__(TPB, 4) void dnf_kernel_nows(
    const float* __restrict__ x,
    const int* __restrict__ feat,
    const int* __restrict__ sign,
    const int* __restrict__ class_conj,
    float* __restrict__ out)
{
    __shared__ __align__(16) uint4 xs4[F_ * 2];   // 128 KB

    const int b0  = blockIdx.x * RROWS;
    const int tid = threadIdx.x;

    for (int f = tid; f < F_; f += TPB) {
        float v0 = x[(size_t)(b0 + 0) * F_ + f];
        float v1 = x[(size_t)(b0 + 1) * F_ + f];
        float v2 = x[(size_t)(b0 + 2) * F_ + f];
        float v3 = x[(size_t)(b0 + 3) * F_ + f];
        float v4 = x[(size_t)(b0 + 4) * F_ + f];
        float v5 = x[(size_t)(b0 + 5) * F_ + f];
        float v6 = x[(size_t)(b0 + 6) * F_ + f];
        float v7 = x[(size_t)(b0 + 7) * F_ + f];
        __half2 n01 = __floats2half2_rn(1.0f - v0, 1.0f - v1);
        __half2 n23 = __floats2half2_rn(1.0f - v2, 1.0f - v3);
        __half2 n45 = __floats2half2_rn(1.0f - v4, 1.0f - v5);
        __half2 n67 = __floats2half2_rn(1.0f - v6, 1.0f - v7);
        __half2 p01 = __floats2half2_rn(v0, v1);
        __half2 p23 = __floats2half2_rn(v2, v3);
        __half2 p45 = __floats2half2_rn(v4, v5);
        __half2 p67 = __floats2half2_rn(v6, v7);
        uint4 neg, pos;
        neg.x = *(unsigned*)&n01; neg.y = *(unsigned*)&n23;
        neg.z = *(unsigned*)&n45; neg.w = *(unsigned*)&n67;
        pos.x = *(unsigned*)&p01; pos.y = *(unsigned*)&p23;
        pos.z = *(unsigned*)&p45; pos.w = *(unsigned*)&p67;
        xs4[(f << 1) | 0] = neg;
        xs4[(f << 1) | 1] = pos;
    }
    __syncthreads();

    const int kk = tid;
    const int4* cc = (const int4*)(class_conj + kk * S_);
    int4 a0 = cc[0], a1 = cc[1];
    int idx[S_] = {a0.x, a0.y, a0.z, a0.w, a1.x, a1.y, a1.z, a1.w};

    __half2 ma, mb, mc, md;
    #pragma unroll
    for (int s = 0; s < S_; ++s) {
        int c = idx[s];
        const int4* fq = (const int4*)(feat + c * T_);
        const int4* sq = (const int4*)(sign + c * T_);
        int4 f0 = fq[0], f1 = fq[1];
        int4 s0 = sq[0], s1 = sq[1];
        __half2 pa, pb, pc, pd;
        unsigned o;
        o = (f0.x << 1) | (s0.x > 0 ? 1 : 0); LIT_INIT(o);
        o = (f0.y << 1) | (s0.y > 0 ? 1 : 0); LIT_MUL(o);
        o = (f0.z << 1) | (s0.z > 0 ? 1 : 0); LIT_MUL(o);
        o = (f0.w << 1) | (s0.w > 0 ? 1 : 0); LIT_MUL(o);
        o = (f1.x << 1) | (s1.x > 0 ? 1 : 0); LIT_MUL(o);
        o = (f1.y << 1) | (s1.y > 0 ? 1 : 0); LIT_MUL(o);
        o = (f1.z << 1) | (s1.z > 0 ? 1 : 0); LIT_MUL(o);
        o = (f1.w << 1) | (s1.w > 0 ? 1 : 0); LIT_MUL(o);
        if (s == 0) { ma = pa; mb = pb; mc = pc; md = pd; }
        else {
            ma = h2max(ma, pa); mb = h2max(mb, pb);
            mc = h2max(mc, pc); md = h2max(md, pd);
        }
    }

    float2 f;
    f = __half22float2(ma); out[(size_t)(b0+0)*K_+kk] = f.x; out[(size_t)(b0+1)*K_+kk] = f.y;
    f = __half22float2(mb); out[(size_t)(b0+2)*K_+kk] = f.x; out[(size_t)(b0+3)*K_+kk] = f.y;
    f = __half22float2(mc); out[(size_t)(b0+4)*K_+kk] = f.x; out[(size_t)(b0+5)*K_+kk] = f.y;
    f = __half22float2(md); out[(size_t)(b0+6)*K_+kk] = f.x; out[(size_t)(b0+7)*K_+kk] = f.y;
}

extern "C" void kernel_launch(void* const* d_in, const int* in_sizes, int n_in,
                              void* d_out, int out_size, void* d_ws, size_t ws_size,
                              hipStream_t stream) {
    const float* x  = (const float*)d_in[0];
    const int* feat = (const int*)d_in[1];
    const int* sign = (const int*)d_in[2];
    const int* ccj  = (const int*)d_in[3];
    float* out      = (float*)d_out;

    const size_t klit_bytes = (size_t)K_ * S_ * sizeof(uint4);  // 128 KB
    if (ws_size >= klit_bytes) {
        uint4* klit = (uint4*)d_ws;
        build_klit_balanced<<<K_ * S_ / 64, 64, 0, stream>>>(feat, sign, ccj, klit);
        dnf_kernel<<<B_ / RROWS, TPB, 0, stream>>>(x, klit, out);
    } else {
        dnf_kernel_nows<<<B_ / RROWS, TPB, 0, stream>>>(x, feat, sign, ccj, out);
    }
}

// Round 14
// 21.937 us; speedup vs baseline: 2.4666x; 2.4666x over previous
//
#include <hip/hip_runtime.h>
#include <hip/hip_fp16.h>

#define B_ 2048
#define F_ 4096
#define C_ 8192
#define T_ 8
#define K_ 1024
#define S_ 8
#define RROWS 8
#define TPB 1024

// ---------------------------------------------------------------------------
// Prepass: klit[s][k] = 8 packed u16 LDS-slot indices ((f<<1)|sgn) of the
// literals of conjunction class_conj[k][s], sorted by bank-group (slot&7)
// and ROTATED by (k&7): main-kernel lane l reads sorted[(j+l)&7] at step j,
// so if a lane's groups are distinct the wave's bank load is PERFECTLY
// balanced; with duplicates it degrades gracefully. Lane-local only — no
// barriers, no atomics (R13's mistake). Product is commutative => exact.
// ---------------------------------------------------------------------------
__global__ __launch_bounds__(256) void build_klit_sorted(
    const int* __restrict__ feat,
    const int* __restrict__ sign,
    const int* __restrict__ class_conj,
    uint4* __restrict__ klit)
{
    int j = blockIdx.x * blockDim.x + threadIdx.x;   // j = s*K_ + k? no: flat
    if (j >= K_ * S_) return;
    int k = j & (K_ - 1);
    int s = j >> 10;                                  // K_=1024

    int c = class_conj[k * S_ + s];
    const int4* fq = (const int4*)(feat + c * T_);
    const int4* sq = (const int4*)(sign + c * T_);
    int4 f0 = fq[0], f1 = fq[1];
    int4 s0 = sq[0], s1 = sq[1];
    unsigned sl[T_];
    sl[0] = (unsigned)((f0.x << 1) | (s0.x > 0 ? 1 : 0));
    sl[1] = (unsigned)((f0.y << 1) | (s0.y > 0 ? 1 : 0));
    sl[2] = (unsigned)((f0.z << 1) | (s0.z > 0 ? 1 : 0));
    sl[3] = (unsigned)((f0.w << 1) | (s0.w > 0 ? 1 : 0));
    sl[4] = (unsigned)((f1.x << 1) | (s1.x > 0 ? 1 : 0));
    sl[5] = (unsigned)((f1.y << 1) | (s1.y > 0 ? 1 : 0));
    sl[6] = (unsigned)((f1.z << 1) | (s1.z > 0 ? 1 : 0));
    sl[7] = (unsigned)((f1.w << 1) | (s1.w > 0 ? 1 : 0));

    // sort by bank-group (slot & 7): Bose-Nelson 19-CE network, fully unrolled
#define CSWP(a, b)                                                   \
    { unsigned ka = sl[a] & 7u, kb = sl[b] & 7u;                     \
      if (ka > kb) { unsigned t = sl[a]; sl[a] = sl[b]; sl[b] = t; } }
    CSWP(0,1) CSWP(2,3) CSWP(4,5) CSWP(6,7)
    CSWP(0,2) CSWP(1,3) CSWP(4,6) CSWP(5,7)
    CSWP(1,2) CSWP(5,6) CSWP(0,4) CSWP(3,7)
    CSWP(1,5) CSWP(2,6)
    CSWP(1,4) CSWP(3,6)
    CSWP(2,4) CSWP(3,5)
    CSWP(3,4)
#undef CSWP

    const int rot = k & 7;                            // lane rotation
    unsigned ch[T_];
    #pragma unroll
    for (int i = 0; i < T_; ++i)
        ch[i] = sl[(i + rot) & 7] & 0xFFFFu;

    uint4 p;
    p.x = ch[0] | (ch[1] << 16);
    p.y = ch[2] | (ch[3] << 16);
    p.z = ch[4] | (ch[5] << 16);
    p.w = ch[6] | (ch[7] << 16);
    klit[s * K_ + k] = p;
}

// packed f16 max: ROCm 7.2 lacks __hmax2; gfx950 has v_pk_max_f16
__device__ __forceinline__ __half2 h2max(__half2 a, __half2 b) {
    unsigned int ua = *(unsigned int*)&a, ub = *(unsigned int*)&b, ur;
    asm("v_pk_max_f16 %0, %1, %2" : "=v"(ur) : "v"(ua), "v"(ub));
    return *(__half2*)&ur;
}

__device__ __forceinline__ __half2 u2h2(unsigned int u) { return *(__half2*)&u; }

// one literal for 8 rows: ONE ds_read_b128 at slot index (direct LDS indexing)
#define LIT_INIT(SLOT)                                              \
    { uint4 g = xs4[SLOT];                                          \
      pa = u2h2(g.x); pb = u2h2(g.y); pc = u2h2(g.z); pd = u2h2(g.w); }
#define LIT_MUL(SLOT)                                               \
    { uint4 g = xs4[SLOT];                                          \
      pa = __hmul2(pa, u2h2(g.x)); pb = __hmul2(pb, u2h2(g.y));     \
      pc = __hmul2(pc, u2h2(g.z)); pd = __hmul2(pd, u2h2(g.w)); }

// one s-step: product of 8 literals (packed in uint4 P), max into m*
#define STEP_FIRST(P)                                               \
    { __half2 pa, pb, pc, pd;                                       \
      LIT_INIT((P).x & 0xFFFFu); LIT_MUL((P).x >> 16);              \
      LIT_MUL ((P).y & 0xFFFFu); LIT_MUL((P).y >> 16);              \
      LIT_MUL ((P).z & 0xFFFFu); LIT_MUL((P).z >> 16);              \
      LIT_MUL ((P).w & 0xFFFFu); LIT_MUL((P).w >> 16);              \
      ma = pa; mb = pb; mc = pc; md = pd; }
#define STEP_NEXT(P)                                                \
    { __half2 pa, pb, pc, pd;                                       \
      LIT_INIT((P).x & 0xFFFFu); LIT_MUL((P).x >> 16);              \
      LIT_MUL ((P).y & 0xFFFFu); LIT_MUL((P).y >> 16);              \
      LIT_MUL ((P).z & 0xFFFFu); LIT_MUL((P).z >> 16);              \
      LIT_MUL ((P).w & 0xFFFFu); LIT_MUL((P).w >> 16);              \
      ma = h2max(ma, pa); mb = h2max(mb, pb);                       \
      mc = h2max(mc, pc); md = h2max(md, pd); }

// ---------------------------------------------------------------------------
// Fused kernel: one 1024-thread block per 8 batch rows; grid=256 = 1 block/CU.
// LDS: one uint4 per (f,s) slot = 8 rows f16 = 128 KB.
// klit loads for all 8 steps hoisted before staging (overlap HBM latency).
// ---------------------------------------------------------------------------
__global__ __launch_bounds__(TPB, 4) void dnf_kernel(
    const float* __restrict__ x,
    const uint4* __restrict__ klit,
    float* __restrict__ out)
{
    __shared__ __align__(16) uint4 xs4[F_ * 2];   // 128 KB: slot = (f<<1)|s

    const int b0  = blockIdx.x * RROWS;
    const int tid = threadIdx.x;
    const int kk  = tid;                          // one class per thread

    // hoisted coalesced index loads (overlap the staging HBM phase)
    uint4 kl0 = klit[0 * K_ + kk];
    uint4 kl1 = klit[1 * K_ + kk];
    uint4 kl2 = klit[2 * K_ + kk];
    uint4 kl3 = klit[3 * K_ + kk];
    uint4 kl4 = klit[4 * K_ + kk];
    uint4 kl5 = klit[5 * K_ + kk];
    uint4 kl6 = klit[6 * K_ + kk];
    uint4 kl7 = klit[7 * K_ + kk];

    // ---- stage 8 rows of x as dual f16 table ----
    for (int f = tid; f < F_; f += TPB) {
        float v0 = x[(size_t)(b0 + 0) * F_ + f];
        float v1 = x[(size_t)(b0 + 1) * F_ + f];
        float v2 = x[(size_t)(b0 + 2) * F_ + f];
        float v3 = x[(size_t)(b0 + 3) * F_ + f];
        float v4 = x[(size_t)(b0 + 4) * F_ + f];
        float v5 = x[(size_t)(b0 + 5) * F_ + f];
        float v6 = x[(size_t)(b0 + 6) * F_ + f];
        float v7 = x[(size_t)(b0 + 7) * F_ + f];
        __half2 n01 = __floats2half2_rn(1.0f - v0, 1.0f - v1);
        __half2 n23 = __floats2half2_rn(1.0f - v2, 1.0f - v3);
        __half2 n45 = __floats2half2_rn(1.0f - v4, 1.0f - v5);
        __half2 n67 = __floats2half2_rn(1.0f - v6, 1.0f - v7);
        __half2 p01 = __floats2half2_rn(v0, v1);
        __half2 p23 = __floats2half2_rn(v2, v3);
        __half2 p45 = __floats2half2_rn(v4, v5);
        __half2 p67 = __floats2half2_rn(v6, v7);
        uint4 neg, pos;
        neg.x = *(unsigned*)&n01; neg.y = *(unsigned*)&n23;
        neg.z = *(unsigned*)&n45; neg.w = *(unsigned*)&n67;
        pos.x = *(unsigned*)&p01; pos.y = *(unsigned*)&p23;
        pos.z = *(unsigned*)&p45; pos.w = *(unsigned*)&p67;
        xs4[(f << 1) | 0] = neg;
        xs4[(f << 1) | 1] = pos;
    }
    __syncthreads();

    __half2 ma, mb, mc, md;
    STEP_FIRST(kl0);
    STEP_NEXT(kl1);
    STEP_NEXT(kl2);
    STEP_NEXT(kl3);
    STEP_NEXT(kl4);
    STEP_NEXT(kl5);
    STEP_NEXT(kl6);
    STEP_NEXT(kl7);

    float2 f;
    f = __half22float2(ma); out[(size_t)(b0+0)*K_+kk] = f.x; out[(size_t)(b0+1)*K_+kk] = f.y;
    f = __half22float2(mb); out[(size_t)(b0+2)*K_+kk] = f.x; out[(size_t)(b0+3)*K_+kk] = f.y;
    f = __half22float2(mc); out[(size_t)(b0+4)*K_+kk] = f.x; out[(size_t)(b0+5)*K_+kk] = f.y;
    f = __half22float2(md); out[(size_t)(b0+6)*K_+kk] = f.x; out[(size_t)(b0+7)*K_+kk] = f.y;
}

// ---------------------------------------------------------------------------
// Fallback (no workspace): inline feat/sign decode, same LDS table.
// ---------------------------------------------------------------------------
__global__ __launch_bounds__(TPB, 4) void dnf_kernel_nows(
    const float* __restrict__ x,
    const int* __restrict__ feat,
    const int* __restrict__ sign,
    const int* __restrict__ class_conj,
    float* __restrict__ out)
{
    __shared__ __align__(16) uint4 xs4[F_ * 2];   // 128 KB

    const int b0  = blockIdx.x * RROWS;
    const int tid = threadIdx.x;

    for (int f = tid; f < F_; f += TPB) {
        float v0 = x[(size_t)(b0 + 0) * F_ + f];
        float v1 = x[(size_t)(b0 + 1) * F_ + f];
        float v2 = x[(size_t)(b0 + 2) * F_ + f];
        float v3 = x[(size_t)(b0 + 3) * F_ + f];
        float v4 = x[(size_t)(b0 + 4) * F_ + f];
        float v5 = x[(size_t)(b0 + 5) * F_ + f];
        float v6 = x[(size_t)(b0 + 6) * F_ + f];
        float v7 = x[(size_t)(b0 + 7) * F_ + f];
        __half2 n01 = __floats2half2_rn(1.0f - v0, 1.0f - v1);
        __half2 n23 = __floats2half2_rn(1.0f - v2, 1.0f - v3);
        __half2 n45 = __floats2half2_rn(1.0f - v4, 1.0f - v5);
        __half2 n67 = __floats2half2_rn(1.0f - v6, 1.0f - v7);
        __half2 p01 = __floats2half2_rn(v0, v1);
        __half2 p23 = __floats2half2_rn(v2, v3);
        __half2 p45 = __floats2half2_rn(v4, v5);
        __half2 p67 = __floats2half2_rn(v6, v7);
        uint4 neg, pos;
        neg.x = *(unsigned*)&n01; neg.y = *(unsigned*)&n23;
        neg.z = *(unsigned*)&n45; neg.w = *(unsigned*)&n67;
        pos.x = *(unsigned*)&p01; pos.y = *(unsigned*)&p23;
        pos.z = *(unsigned*)&p45; pos.w = *(unsigned*)&p67;
        xs4[(f << 1) | 0] = neg;
        xs4[(f << 1) | 1] = pos;
    }
    __syncthreads();

    const int kk = tid;
    const int4* cc = (const int4*)(class_conj + kk * S_);
    int4 a0 = cc[0], a1 = cc[1];
    int idx[S_] = {a0.x, a0.y, a0.z, a0.w, a1.x, a1.y, a1.z, a1.w};

    __half2 ma, mb, mc, md;
    #pragma unroll
    for (int s = 0; s < S_; ++s) {
        int c = idx[s];
        const int4* fq = (const int4*)(feat + c * T_);
        const int4* sq = (const int4*)(sign + c * T_);
        int4 f0 = fq[0], f1 = fq[1];
        int4 s0 = sq[0], s1 = sq[1];
        __half2 pa, pb, pc, pd;
        unsigned o;
        o = (f0.x << 1) | (s0.x > 0 ? 1 : 0); LIT_INIT(o);
        o = (f0.y << 1) | (s0.y > 0 ? 1 : 0); LIT_MUL(o);
        o = (f0.z << 1) | (s0.z > 0 ? 1 : 0); LIT_MUL(o);
        o = (f0.w << 1) | (s0.w > 0 ? 1 : 0); LIT_MUL(o);
        o = (f1.x << 1) | (s1.x > 0 ? 1 : 0); LIT_MUL(o);
        o = (f1.y << 1) | (s1.y > 0 ? 1 : 0); LIT_MUL(o);
        o = (f1.z << 1) | (s1.z > 0 ? 1 : 0); LIT_MUL(o);
        o = (f1.w << 1) | (s1.w > 0 ? 1 : 0); LIT_MUL(o);
        if (s == 0) { ma = pa; mb = pb; mc = pc; md = pd; }
        else {
            ma = h2max(ma, pa); mb = h2max(mb, pb);
            mc = h2max(mc, pc); md = h2max(md, pd);
        }
    }

    float2 f;
    f = __half22float2(ma); out[(size_t)(b0+0)*K_+kk] = f.x; out[(size_t)(b0+1)*K_+kk] = f.y;
    f = __half22float2(mb); out[(size_t)(b0+2)*K_+kk] = f.x; out[(size_t)(b0+3)*K_+kk] = f.y;
    f = __half22float2(mc); out[(size_t)(b0+4)*K_+kk] = f.x; out[(size_t)(b0+5)*K_+kk] = f.y;
    f = __half22float2(md); out[(size_t)(b0+6)*K_+kk] = f.x; out[(size_t)(b0+7)*K_+kk] = f.y;
}

extern "C" void kernel_launch(void* const* d_in, const int* in_sizes, int n_in,
                              void* d_out, int out_size, void* d_ws, size_t ws_size,
                              hipStream_t stream) {
    const float* x  = (const float*)d_in[0];
    const int* feat = (const int*)d_in[1];
    const int* sign = (const int*)d_in[2];
    const int* ccj  = (const int*)d_in[3];
    float* out      = (float*)d_out;

    const size_t klit_bytes = (size_t)K_ * S_ * sizeof(uint4);  // 128 KB
    if (ws_size >= klit_bytes) {
        uint4* klit = (uint4*)d_ws;
        build_klit_sorted<<<(K_ * S_ + 255) / 256, 256, 0, stream>>>(feat, sign, ccj, klit);
        dnf_kernel<<<B_ / RROWS, TPB, 0, stream>>>(x, klit, out);
    } else {
        dnf_kernel_nows<<<B_ / RROWS, TPB, 0, stream>>>(x, feat, sign, ccj, out);
    }
}